// Round 6
// baseline (450.793 us; speedup 1.0000x reference)
//
#include <hip/hip_runtime.h>
#include <hip/hip_bf16.h>

// Problem constants (match reference)
#define B_  32
#define C_  3
#define HW_ 1024          // N = H*W
#define L_  8             // alphabet
#define P_  16
#define M_  1024
#define NRUN_S  (B_*C_)           // 96
#define NRUN_P  (C_*P_)           // 48
#define NRUN_SP (B_*C_*P_)        // 1536
// Tight dictionary bound for len-2048 LZW over alphabet 8:
// 64 len-2 + 512 len-3 + 320 len-4 = 896 entries max; nfree <= 8+896 = 904.
#define TRIE_N  904
#define DUMMY_OFF (TRIE_N * L_ * 2)   // byte offset of dummy (scratch) entry

// ---------------------------------------------------------------------------
// Kernel 1: quantize  strings[b,c,n] = argmin_l |x[b,c,curve[n]] - levels[c,l]|
// ---------------------------------------------------------------------------
__global__ void quantize_kernel(const float* __restrict__ x,
                                const int* __restrict__ curve,
                                const float* __restrict__ levels,
                                unsigned char* __restrict__ strings) {
    int idx = blockIdx.x * blockDim.x + threadIdx.x;   // [0, 96*1024)
    if (idx >= NRUN_S * HW_) return;
    int n  = idx & (HW_ - 1);
    int bc = idx >> 10;            // b*3 + c
    int c  = bc % C_;
    int pix = curve[n];
    float v = x[bc * HW_ + pix];
    float best = fabsf(v - levels[c * L_ + 0]);
    int bi = 0;
#pragma unroll
    for (int l = 1; l < L_; ++l) {
        float d = fabsf(v - levels[c * L_ + l]);
        if (d < best) { best = d; bi = l; }   // strict < : first-min (matches jnp.argmin)
    }
    strings[idx] = (unsigned char)bi;
}

// ---------------------------------------------------------------------------
// Kernel 2: LZW count per run. One block (64 threads) per run.
// Serial walker (lane 0) with:
//   - sentinel init: empty entry trie[node][c] = c  (r<8 <=> miss, r = restart)
//   - deferred writes (up to 2 pending), distance-1 hazard fixups
//   - DEPTH-2 MISS SPECULATION: per iteration issue
//       r0 = trie[cur][c0]  and  r1 = trie[c0][c1]
//     (both addresses known before issue). Hit: consume c0. Miss: restart is
//     c0, so r1 resolves the next symbol too -> consume c0,c1 in ONE round
//     trip. Iterations = len-1-misses (~30% fewer round trips).
//   - variable-advance symbol window (funnel over w0:w1) is OFF the chain.
// ---------------------------------------------------------------------------
__global__ void __launch_bounds__(64)
lzw_kernel(const unsigned char* __restrict__ strings,
           const int* __restrict__ pmaps,
           int* __restrict__ cs, int* __restrict__ cp, int* __restrict__ csp) {
    __shared__ unsigned short trie[TRIE_N * L_ + 8]; // +8: dummy slot
    __shared__ unsigned long long nib[136];          // 16 syms per u64

    const int run = blockIdx.x;
    const int tid = threadIdx.x;

    // parallel sentinel init: entry e holds (e & 7)
    unsigned int* trie32 = (unsigned int*)trie;
    for (int i = tid; i < TRIE_N * L_ / 2; i += 64) {
        unsigned c0 = (i & 3) << 1;
        trie32[i] = c0 | ((c0 + 1) << 16);
    }

    int len = 0;
    const unsigned char* sp = nullptr;
    const int* pp = nullptr;
    int pbase = 0;   // u64 index where pmap nibbles start

    if (run < NRUN_S) {
        sp = strings + run * HW_;  len = HW_;
    } else if (run < NRUN_S + NRUN_P) {
        int idx = run - NRUN_S;                 // c*16 + p
        pp = pmaps + idx * M_;  len = M_;  pbase = 0;
    } else {
        int idx = run - (NRUN_S + NRUN_P);      // (b*3+c)*16 + p
        int bc = idx >> 4;
        int c  = bc % C_;
        int p  = idx & 15;
        sp = strings + bc * HW_;
        pp = pmaps + (c * P_ + p) * M_;
        len = HW_ + M_;  pbase = HW_ / 16;      // 64
    }

    if (sp) {  // 1024 string bytes -> 64 u64s; thread i packs bytes [16i,16i+16)
        const int4* s4 = (const int4*)sp;
        int4 v = s4[tid];
        unsigned long long r = 0;
        unsigned u;
        u = (unsigned)v.x; r |= (unsigned long long)((u & 7u) | ((u >> 4) & 0x70u) | ((u >> 8) & 0x700u) | ((u >> 12) & 0x7000u));
        u = (unsigned)v.y; r |= (unsigned long long)((u & 7u) | ((u >> 4) & 0x70u) | ((u >> 8) & 0x700u) | ((u >> 12) & 0x7000u)) << 16;
        u = (unsigned)v.z; r |= (unsigned long long)((u & 7u) | ((u >> 4) & 0x70u) | ((u >> 8) & 0x700u) | ((u >> 12) & 0x7000u)) << 32;
        u = (unsigned)v.w; r |= (unsigned long long)((u & 7u) | ((u >> 4) & 0x70u) | ((u >> 8) & 0x700u) | ((u >> 12) & 0x7000u)) << 48;
        nib[tid] = r;
    }
    if (pp) {  // 1024 pmap ints -> 64 u64s
        const int4* p4 = (const int4*)pp;
        unsigned long long r = 0;
#pragma unroll
        for (int k = 0; k < 4; ++k) {
            int4 q = p4[tid * 4 + k];
            unsigned part = (unsigned)(q.x & 7) | ((unsigned)(q.y & 7) << 4) |
                            ((unsigned)(q.z & 7) << 8) | ((unsigned)(q.w & 7) << 12);
            r |= (unsigned long long)part << (16 * k);
        }
        nib[pbase + tid] = r;
    }
    // zero pad u64s past the data (speculative lookahead reads past the end)
    {
        int nu64 = len >> 4;
        if (tid < 8) nib[nu64 + tid] = 0;
    }
    __syncthreads();

    if (tid == 0) {
        const char* tb = (const char*)trie;
        char* tw = (char*)trie;

        unsigned long long w0 = nib[0], w1 = nib[1];
        int pos = 2;
        int bp  = 4;                        // bit pos of first unconsumed symbol
        int cur = (int)(w0 & 7);
        int nfree = L_;
        int ap0 = DUMMY_OFF, vp0 = 8, ap1 = DUMMY_OFF, vp1 = 8;

        unsigned long long sw = (w0 >> 4) | (w1 << 60);
        int c0 = (int)(sw & 7);
        int c1 = (int)((sw >> 4) & 7);
        int a0 = (cur << 4) + (c0 << 1);
        int a1 = (c0  << 4) + (c1 << 1);
        int r0 = *(const unsigned short*)(tb + a0);   // preloop issue
        int r1 = *(const unsigned short*)(tb + a1);

        int rem = len - 1;
        while (rem >= 2) {
            // ---- wait + fixups (chain) ----
            int r0f = (a0 == ap0) ? vp0 : r0;
            r0f     = (a0 == ap1) ? vp1 : r0f;
            int m0  = (r0f < 8) ? 1 : 0;
            int r1f = (a1 == ap0) ? vp0 : r1;
            r1f     = (a1 == ap1) ? vp1 : r1f;
            r1f     = (m0 && (a1 == a0)) ? nfree : r1f;   // same-iter insert
            int m1  = (r1f < 8) ? 1 : 0;
            cur = m0 ? r1f : r0f;

            // ---- next symbols (off-chain: from pre-advance window) ----
            int s1 = (int)((sw >> 4) & 7);
            int s2 = (int)((sw >> 8) & 7);
            int s3 = (int)((sw >> 12) & 7);
            int sn0 = m0 ? s2 : s1;
            int sn1 = m0 ? s3 : s2;

            int na0 = (cur << 4) + (sn0 << 1);            // chain: lshl_add
            int na1 = (sn0 << 4) + (sn1 << 1);

            // ---- inserts (deferred; written after next reads issue) ----
            int e0a = m0 ? a0 : DUMMY_OFF;
            int e1a = (m0 & m1) ? a1 : DUMMY_OFF;
            int e0v = nfree;
            int e1v = nfree + 1;
            nfree += m0 + (m0 & m1);
            rem   -= 1 + m0;

            // ---- issue next reads, then writes (writes hide in flight) ----
            int nr0 = *(const unsigned short*)(tb + na0);
            int nr1 = *(const unsigned short*)(tb + na1);
            *(unsigned short*)(tw + e0a) = (unsigned short)e0v;
            *(unsigned short*)(tw + e1a) = (unsigned short)e1v;

            a0 = na0; a1 = na1; r0 = nr0; r1 = nr1;
            ap0 = e0a; vp0 = e0v; ap1 = e1a; vp1 = e1v;

            // ---- window advance (off-chain) ----
            bp += 4 + 4 * m0;
            if (bp >= 64) { bp -= 64; w0 = w1; w1 = nib[pos]; pos++; }
            sw = (w0 >> bp) | (bp ? (w1 << (64 - bp)) : 0ULL);
        }
        // tail: 0 or 1 symbols; r0 for it is already in flight
        if (rem == 1) {
            int r0f = (a0 == ap0) ? vp0 : r0;
            r0f     = (a0 == ap1) ? vp1 : r0f;
            if (r0f < 8) nfree++;
        }

        int result = (nfree - L_) + 1;
        if (run < NRUN_S)                cs[run] = result;
        else if (run < NRUN_S + NRUN_P)  cp[run - NRUN_S] = result;
        else                             csp[run - (NRUN_S + NRUN_P)] = result;
    }
}

// ---------------------------------------------------------------------------
// Kernel 3: NCD epilogue
// ---------------------------------------------------------------------------
__global__ void ncd_kernel(const int* __restrict__ cs,
                           const int* __restrict__ cp,
                           const int* __restrict__ csp,
                           float* __restrict__ out) {
    int idx = blockIdx.x * blockDim.x + threadIdx.x;
    if (idx >= NRUN_SP) return;
    int p  = idx & 15;
    int bc = idx >> 4;         // b*3 + c
    int c  = bc % C_;
    float a  = (float)cs[bc];
    float b  = (float)cp[c * P_ + p];
    float ab = (float)csp[idx];
    out[idx] = (ab - fminf(a, b)) / fmaxf(a, b);
}

// ---------------------------------------------------------------------------
extern "C" void kernel_launch(void* const* d_in, const int* in_sizes, int n_in,
                              void* d_out, int out_size, void* d_ws, size_t ws_size,
                              hipStream_t stream) {
    const float* x      = (const float*)d_in[0];   // [B,C,H,W] f32
    const int*   curve  = (const int*)d_in[1];     // [N] int32
    const float* levels = (const float*)d_in[2];   // [C,L] f32
    const int*   pmaps  = (const int*)d_in[3];     // [C,P,M] int32
    // d_in[4] = i (unused)

    float* out = (float*)d_out;

    unsigned char* strings = (unsigned char*)d_ws;            // 96*1024 bytes
    int* cs  = (int*)((char*)d_ws + NRUN_S * HW_);            // 96
    int* cp  = cs + NRUN_S;                                   // 48
    int* csp = cp + NRUN_P;                                   // 1536

    quantize_kernel<<<(NRUN_S * HW_ + 255) / 256, 256, 0, stream>>>(x, curve, levels, strings);
    lzw_kernel<<<NRUN_S + NRUN_P + NRUN_SP, 64, 0, stream>>>(strings, pmaps, cs, cp, csp);
    ncd_kernel<<<(NRUN_SP + 255) / 256, 256, 0, stream>>>(cs, cp, csp, out);
}

// Round 7
// 348.384 us; speedup vs baseline: 1.2940x; 1.2940x over previous
//
#include <hip/hip_runtime.h>
#include <hip/hip_bf16.h>

// Problem constants (match reference)
#define B_  32
#define C_  3
#define HW_ 1024          // N = H*W
#define L_  8             // alphabet
#define P_  16
#define M_  1024
#define NRUN_S  (B_*C_)           // 96
#define NRUN_P  (C_*P_)           // 48
#define NRUN_SP (B_*C_*P_)        // 1536
// Tight dictionary bound for len-2048 LZW over alphabet 8:
// 64 len-2 + 512 len-3 + 320 len-4 = 896 entries max; nfree <= 8+896 = 904.
#define TRIE_N  904
#define DUMMY_OFF (TRIE_N * L_ * 2)   // byte offset of dummy (scratch) entry

// ---------------------------------------------------------------------------
// Kernel 1: quantize  strings[b,c,n] = argmin_l |x[b,c,curve[n]] - levels[c,l]|
// ---------------------------------------------------------------------------
__global__ void quantize_kernel(const float* __restrict__ x,
                                const int* __restrict__ curve,
                                const float* __restrict__ levels,
                                unsigned char* __restrict__ strings) {
    int idx = blockIdx.x * blockDim.x + threadIdx.x;   // [0, 96*1024)
    if (idx >= NRUN_S * HW_) return;
    int n  = idx & (HW_ - 1);
    int bc = idx >> 10;            // b*3 + c
    int c  = bc % C_;
    int pix = curve[n];
    float v = x[bc * HW_ + pix];
    float best = fabsf(v - levels[c * L_ + 0]);
    int bi = 0;
#pragma unroll
    for (int l = 1; l < L_; ++l) {
        float d = fabsf(v - levels[c * L_ + l]);
        if (d < best) { best = d; bi = l; }   // strict < : first-min (matches jnp.argmin)
    }
    strings[idx] = (unsigned char)bi;
}

// ---------------------------------------------------------------------------
// Kernel 2: LZW count per run. One block (64 threads) per run.
// Serial walker (lane 0):
//   - sentinel trie init: empty entry trie[n][c] = c  (r<8 <=> miss, and r is
//     then exactly the restart symbol).
//   - depth-2 miss speculation: per iteration probe
//       a0 = (cur, s[si])  and  a1 = (s[si], s[si+1])
//     hit -> consume 1 (cur=r0); miss -> restart is s[si], so r1 resolves the
//     second symbol in the SAME round trip (consume 2).
//   - deferred writes (2 pending) with distance-1 cndmask fixups; same-iter
//     a1==a0 insert handled via nfree forwarding. (Logic bit-validated in r6.)
//   - symbols are PRE-SHIFTED bytes (sym<<1) in LDS; the next iteration's 3
//     symbol bytes are fetched by exact-address ds_read_u8 issued right after
//     the trie reads -- no shift window, no funnel, no in-body branches.
// ---------------------------------------------------------------------------
__global__ void __launch_bounds__(64)
lzw_kernel(const unsigned char* __restrict__ strings,
           const int* __restrict__ pmaps,
           int* __restrict__ cs, int* __restrict__ cp, int* __restrict__ csp) {
    __shared__ unsigned short trie[TRIE_N * L_ + 8];           // 14480 B
    __shared__ __align__(16) unsigned char seq[2 * HW_ + 16];  // sym<<1 bytes

    const int run = blockIdx.x;
    const int tid = threadIdx.x;

    // parallel sentinel init: entry e holds (e & 7)
    unsigned int* trie32 = (unsigned int*)trie;
    for (int i = tid; i < TRIE_N * L_ / 2; i += 64) {
        unsigned c0 = (i & 3) << 1;
        trie32[i] = c0 | ((c0 + 1) << 16);
    }

    int len = 0;
    const unsigned char* sp = nullptr;
    const int* pp = nullptr;
    int poff = 0;   // byte offset where pmap symbols start in seq

    if (run < NRUN_S) {
        sp = strings + run * HW_;  len = HW_;
    } else if (run < NRUN_S + NRUN_P) {
        int idx = run - NRUN_S;                 // c*16 + p
        pp = pmaps + idx * M_;  len = M_;  poff = 0;
    } else {
        int idx = run - (NRUN_S + NRUN_P);      // (b*3+c)*16 + p
        int bc = idx >> 4;
        int c  = bc % C_;
        int p  = idx & 15;
        sp = strings + bc * HW_;
        pp = pmaps + (c * P_ + p) * M_;
        len = HW_ + M_;  poff = HW_;
    }

    if (sp) {  // 1024 string bytes -> pre-shifted bytes, 16B per lane
        int4 v = ((const int4*)sp)[tid];
        int4 o;
        o.x = (v.x << 1) & 0x0E0E0E0E;
        o.y = (v.y << 1) & 0x0E0E0E0E;
        o.z = (v.z << 1) & 0x0E0E0E0E;
        o.w = (v.w << 1) & 0x0E0E0E0E;
        ((int4*)seq)[tid] = o;
    }
    if (pp) {  // 1024 pmap ints -> pre-shifted bytes, 16 ints -> 16B per lane
        const int4* p4 = (const int4*)pp;
        int4 q0 = p4[tid * 4 + 0];
        int4 q1 = p4[tid * 4 + 1];
        int4 q2 = p4[tid * 4 + 2];
        int4 q3 = p4[tid * 4 + 3];
        int4 o;
        o.x = ((q0.x & 7) << 1) | ((q0.y & 7) << 9) | ((q0.z & 7) << 17) | ((q0.w & 7) << 25);
        o.y = ((q1.x & 7) << 1) | ((q1.y & 7) << 9) | ((q1.z & 7) << 17) | ((q1.w & 7) << 25);
        o.z = ((q2.x & 7) << 1) | ((q2.y & 7) << 9) | ((q2.z & 7) << 17) | ((q2.w & 7) << 25);
        o.w = ((q3.x & 7) << 1) | ((q3.y & 7) << 9) | ((q3.z & 7) << 17) | ((q3.w & 7) << 25);
        ((int4*)(seq + poff))[tid] = o;
    }
    if (tid < 4) ((int*)(seq + len))[tid] = 0;   // 16B zero pad (prefetch OOB)
    __syncthreads();

    if (tid == 0) {
        const char* tb = (const char*)trie;
        char* tw = (char*)trie;

        int cur = seq[0] >> 1;
        int v1  = seq[1], v2 = seq[2];
        int x2  = seq[2], x3 = seq[3], x4 = seq[4];   // s[si+1..si+3], si=1
        int a0  = (cur << 4) + v1;
        int a1  = (v1  << 3) + v2;
        int r0  = *(const unsigned short*)(tb + a0);
        int r1  = *(const unsigned short*)(tb + a1);
        int ap0 = DUMMY_OFF, vp0 = 8, ap1 = DUMMY_OFF, vp1 = 8;
        int nfree = L_;
        int rem = len - 1;    // symbols left to consume
        int si  = 1;          // index of symbol probed by a0

        while (rem >= 2) {
            // ---- wait + fixups (the chain) ----
            int r0f = (a0 == ap0) ? vp0 : r0;
            r0f     = (a0 == ap1) ? vp1 : r0f;
            int m0  = (r0f < 8) ? 1 : 0;
            int r1f = (a1 == ap0) ? vp0 : r1;
            r1f     = (a1 == ap1) ? vp1 : r1f;
            r1f     = (m0 & (a1 == a0)) ? nfree : r1f;   // same-iter insert fwd
            int m1  = (r1f < 8) ? 1 : 0;
            cur = m0 ? r1f : r0f;

            // ---- next addresses (x2..x4 prefetched last iter, pre-shifted) --
            int nv1 = m0 ? x3 : x2;
            int nv2 = m0 ? x4 : x3;
            int na0 = (cur << 4) + nv1;
            int na1 = (nv1 << 3) + nv2;
            int nr0 = *(const unsigned short*)(tb + na0);   // issue reads
            int nr1 = *(const unsigned short*)(tb + na1);

            // ---- exact-address symbol prefetch for NEXT iteration ----
            si += 1 + m0;
            int f2 = seq[si + 1], f3 = seq[si + 2], f4 = seq[si + 3];

            // ---- deferred dictionary writes (issued after the reads) ----
            int w0v = nfree, w1v = nfree + 1;
            int e0a = m0 ? a0 : DUMMY_OFF;
            int e1a = (m0 & m1) ? a1 : DUMMY_OFF;
            *(unsigned short*)(tw + e0a) = (unsigned short)w0v;
            *(unsigned short*)(tw + e1a) = (unsigned short)w1v;

            nfree += m0 + (m0 & m1);
            rem   -= 1 + m0;
            a0 = na0; a1 = na1; r0 = nr0; r1 = nr1;
            ap0 = e0a; vp0 = w0v; ap1 = e1a; vp1 = w1v;
            x2 = f2; x3 = f3; x4 = f4;
        }
        if (rem == 1) {   // final symbol; its r0 is already in flight
            int r0f = (a0 == ap0) ? vp0 : r0;
            r0f     = (a0 == ap1) ? vp1 : r0f;
            if (r0f < 8) nfree++;
        }

        int result = (nfree - L_) + 1;
        if (run < NRUN_S)                cs[run] = result;
        else if (run < NRUN_S + NRUN_P)  cp[run - NRUN_S] = result;
        else                             csp[run - (NRUN_S + NRUN_P)] = result;
    }
}

// ---------------------------------------------------------------------------
// Kernel 3: NCD epilogue
// ---------------------------------------------------------------------------
__global__ void ncd_kernel(const int* __restrict__ cs,
                           const int* __restrict__ cp,
                           const int* __restrict__ csp,
                           float* __restrict__ out) {
    int idx = blockIdx.x * blockDim.x + threadIdx.x;
    if (idx >= NRUN_SP) return;
    int p  = idx & 15;
    int bc = idx >> 4;         // b*3 + c
    int c  = bc % C_;
    float a  = (float)cs[bc];
    float b  = (float)cp[c * P_ + p];
    float ab = (float)csp[idx];
    out[idx] = (ab - fminf(a, b)) / fmaxf(a, b);
}

// ---------------------------------------------------------------------------
extern "C" void kernel_launch(void* const* d_in, const int* in_sizes, int n_in,
                              void* d_out, int out_size, void* d_ws, size_t ws_size,
                              hipStream_t stream) {
    const float* x      = (const float*)d_in[0];   // [B,C,H,W] f32
    const int*   curve  = (const int*)d_in[1];     // [N] int32
    const float* levels = (const float*)d_in[2];   // [C,L] f32
    const int*   pmaps  = (const int*)d_in[3];     // [C,P,M] int32
    // d_in[4] = i (unused)

    float* out = (float*)d_out;

    unsigned char* strings = (unsigned char*)d_ws;            // 96*1024 bytes
    int* cs  = (int*)((char*)d_ws + NRUN_S * HW_);            // 96
    int* cp  = cs + NRUN_S;                                   // 48
    int* csp = cp + NRUN_P;                                   // 1536

    quantize_kernel<<<(NRUN_S * HW_ + 255) / 256, 256, 0, stream>>>(x, curve, levels, strings);
    lzw_kernel<<<NRUN_S + NRUN_P + NRUN_SP, 64, 0, stream>>>(strings, pmaps, cs, cp, csp);
    ncd_kernel<<<(NRUN_SP + 255) / 256, 256, 0, stream>>>(cs, cp, csp, out);
}

// Round 8
// 128.583 us; speedup vs baseline: 3.5059x; 2.7094x over previous
//
#include <hip/hip_runtime.h>
#include <hip/hip_bf16.h>

// Problem constants (match reference)
#define B_  32
#define C_  3
#define HW_ 1024          // N = H*W
#define L_  8             // alphabet
#define P_  16
#define M_  1024
#define NRUN_S  (B_*C_)           // 96
#define NRUN_P  (C_*P_)           // 48
#define NRUN_SP (B_*C_*P_)        // 1536
// Tight dictionary bound for len-2048 LZW over alphabet 8:
// 64 len-2 + 512 len-3 + 320 len-4 = 896 entries max; nfree <= 8+896 = 904.
#define TRIE_N  904
#define DUMMY_OFF (TRIE_N * L_ * 2)   // byte offset of dummy (scratch) entry

// ---------------------------------------------------------------------------
// Kernel 1: quantize  strings[b,c,n] = argmin_l |x[b,c,curve[n]] - levels[c,l]|
// ---------------------------------------------------------------------------
__global__ void quantize_kernel(const float* __restrict__ x,
                                const int* __restrict__ curve,
                                const float* __restrict__ levels,
                                unsigned char* __restrict__ strings) {
    int idx = blockIdx.x * blockDim.x + threadIdx.x;   // [0, 96*1024)
    if (idx >= NRUN_S * HW_) return;
    int n  = idx & (HW_ - 1);
    int bc = idx >> 10;            // b*3 + c
    int c  = bc % C_;
    int pix = curve[n];
    float v = x[bc * HW_ + pix];
    float best = fabsf(v - levels[c * L_ + 0]);
    int bi = 0;
#pragma unroll
    for (int l = 1; l < L_; ++l) {
        float d = fabsf(v - levels[c * L_ + l]);
        if (d < best) { best = d; bi = l; }   // strict < : first-min (matches jnp.argmin)
    }
    strings[idx] = (unsigned char)bi;
}

// ---------------------------------------------------------------------------
// Kernel 2: LZW count per run. One block (64 threads) per run.
// Minimal-latency serial walker (lane 0):
//   - sentinel init: empty entry trie[node][c] = c, so r<8 <=> miss and r is
//     then the restart symbol -> `cur = r` unconditionally.
//   - DEFERRED WRITE: the dictionary write from step t is issued AFTER the
//     read of step t+1 (reads issue first in program order). The only hazard
//     is a_{t+1}==a_t (e.g. "aaa"); fixed by r = (a==ap)?vp:r_raw, with the
//     compare precomputed while the read is in flight. Distance>=2 is safe
//     (DS pipe processes same-wave ops in program order).
//   - on hit the pending write targets a DUMMY slot (branchless).
//   - chain per step: waitcnt -> cndmask(fixup) -> lshl_add -> ds_read.
//     Measured 148 cy/step = 120 (LDS latency floor) + 28 overhead.
// ---------------------------------------------------------------------------
__global__ void __launch_bounds__(64)
lzw_kernel(const unsigned char* __restrict__ strings,
           const int* __restrict__ pmaps,
           int* __restrict__ cs, int* __restrict__ cp, int* __restrict__ csp) {
    __shared__ unsigned short trie[TRIE_N * L_ + 8]; // +8: dummy slot (16 B)
    __shared__ unsigned long long nib[136];          // 1088 B, 16 syms per u64

    const int run = blockIdx.x;
    const int tid = threadIdx.x;

    // parallel sentinel init: entry e holds (e & 7). 32-bit store covers
    // entries 2i (even c0) and 2i+1 (c0+1).
    unsigned int* trie32 = (unsigned int*)trie;
    for (int i = tid; i < TRIE_N * L_ / 2; i += 64) {
        unsigned c0 = (i & 3) << 1;
        trie32[i] = c0 | ((c0 + 1) << 16);
    }

    int len = 0;
    const unsigned char* sp = nullptr;
    const int* pp = nullptr;
    int pbase = 0;   // u64 index where pmap nibbles start

    if (run < NRUN_S) {
        sp = strings + run * HW_;  len = HW_;
    } else if (run < NRUN_S + NRUN_P) {
        int idx = run - NRUN_S;                 // c*16 + p
        pp = pmaps + idx * M_;  len = M_;  pbase = 0;
    } else {
        int idx = run - (NRUN_S + NRUN_P);      // (b*3+c)*16 + p
        int bc = idx >> 4;
        int c  = bc % C_;
        int p  = idx & 15;
        sp = strings + bc * HW_;
        pp = pmaps + (c * P_ + p) * M_;
        len = HW_ + M_;  pbase = HW_ / 16;      // 64
    }

    if (sp) {  // 1024 string bytes -> 64 u64s; thread i packs bytes [16i,16i+16)
        const int4* s4 = (const int4*)sp;
        int4 v = s4[tid];
        unsigned long long r = 0;
        unsigned u;
        u = (unsigned)v.x; r |= (unsigned long long)((u & 7u) | ((u >> 4) & 0x70u) | ((u >> 8) & 0x700u) | ((u >> 12) & 0x7000u));
        u = (unsigned)v.y; r |= (unsigned long long)((u & 7u) | ((u >> 4) & 0x70u) | ((u >> 8) & 0x700u) | ((u >> 12) & 0x7000u)) << 16;
        u = (unsigned)v.z; r |= (unsigned long long)((u & 7u) | ((u >> 4) & 0x70u) | ((u >> 8) & 0x700u) | ((u >> 12) & 0x7000u)) << 32;
        u = (unsigned)v.w; r |= (unsigned long long)((u & 7u) | ((u >> 4) & 0x70u) | ((u >> 8) & 0x700u) | ((u >> 12) & 0x7000u)) << 48;
        nib[tid] = r;
    }
    if (pp) {  // 1024 pmap ints -> 64 u64s; thread i packs ints [16i,16i+16)
        const int4* p4 = (const int4*)pp;
        unsigned long long r = 0;
#pragma unroll
        for (int k = 0; k < 4; ++k) {
            int4 q = p4[tid * 4 + k];
            unsigned part = (unsigned)(q.x & 7) | ((unsigned)(q.y & 7) << 4) |
                            ((unsigned)(q.z & 7) << 8) | ((unsigned)(q.w & 7) << 12);
            r |= (unsigned long long)part << (16 * k);
        }
        nib[pbase + tid] = r;
    }
    // zero pad u64s past the data (prefetch reads one past the end)
    {
        int nu64 = len >> 4;
        if (tid < 8) nib[nu64 + tid] = 0;
    }
    __syncthreads();

    if (tid == 0) {
        const char* tb = (const char*)trie;
        char* tw = (char*)trie;
        int nfree = L_, cnt = 0;
        int ap = DUMMY_OFF, vp = 8;      // pending write (byte addr, value)

        unsigned long long w = nib[0];
        int cur = (int)(w & 7);
        w >>= 4;
        const int nu64 = len >> 4;
        unsigned long long wnext = nib[1];

        // chain: cndmask(fixup) -> lshl_add -> ds_read. Write trails (issued
        // after the read; distance-1 hazard handled by the fixup).
#define LZW_STEP(S2)                                                      \
        {                                                                 \
            int a = (cur << 4) + (S2);                                    \
            int r_raw = *(const unsigned short*)(tb + a);                 \
            *(unsigned short*)(tw + ap) = (unsigned short)vp;             \
            int r = (a == ap) ? vp : r_raw;                               \
            int m = (r < 8) ? 1 : 0;                                      \
            ap = m ? a : DUMMY_OFF;                                       \
            vp = nfree;                                                   \
            nfree += m; cnt += m;                                         \
            cur = r;                                                      \
        }

#pragma unroll
        for (int j = 0; j < 15; ++j) {
            int s2 = ((int)((w >> (4 * j)) & 7)) << 1;
            LZW_STEP(s2);
        }
        for (int k = 1; k < nu64; ++k) {
            unsigned long long wk = wnext;
            wnext = nib[k + 1];
#pragma unroll
            for (int j = 0; j < 16; ++j) {
                int s2 = ((int)((wk >> (4 * j)) & 7)) << 1;
                LZW_STEP(s2);
            }
        }
#undef LZW_STEP

        int result = cnt + 1;
        if (run < NRUN_S)                cs[run] = result;
        else if (run < NRUN_S + NRUN_P)  cp[run - NRUN_S] = result;
        else                             csp[run - (NRUN_S + NRUN_P)] = result;
    }
}

// ---------------------------------------------------------------------------
// Kernel 3: NCD epilogue
// ---------------------------------------------------------------------------
__global__ void ncd_kernel(const int* __restrict__ cs,
                           const int* __restrict__ cp,
                           const int* __restrict__ csp,
                           float* __restrict__ out) {
    int idx = blockIdx.x * blockDim.x + threadIdx.x;
    if (idx >= NRUN_SP) return;
    int p  = idx & 15;
    int bc = idx >> 4;         // b*3 + c
    int c  = bc % C_;
    float a  = (float)cs[bc];
    float b  = (float)cp[c * P_ + p];
    float ab = (float)csp[idx];
    out[idx] = (ab - fminf(a, b)) / fmaxf(a, b);
}

// ---------------------------------------------------------------------------
extern "C" void kernel_launch(void* const* d_in, const int* in_sizes, int n_in,
                              void* d_out, int out_size, void* d_ws, size_t ws_size,
                              hipStream_t stream) {
    const float* x      = (const float*)d_in[0];   // [B,C,H,W] f32
    const int*   curve  = (const int*)d_in[1];     // [N] int32
    const float* levels = (const float*)d_in[2];   // [C,L] f32
    const int*   pmaps  = (const int*)d_in[3];     // [C,P,M] int32
    // d_in[4] = i (unused)

    float* out = (float*)d_out;

    unsigned char* strings = (unsigned char*)d_ws;            // 96*1024 bytes
    int* cs  = (int*)((char*)d_ws + NRUN_S * HW_);            // 96
    int* cp  = cs + NRUN_S;                                   // 48
    int* csp = cp + NRUN_P;                                   // 1536

    quantize_kernel<<<(NRUN_S * HW_ + 255) / 256, 256, 0, stream>>>(x, curve, levels, strings);
    lzw_kernel<<<NRUN_S + NRUN_P + NRUN_SP, 64, 0, stream>>>(strings, pmaps, cs, cp, csp);
    ncd_kernel<<<(NRUN_SP + 255) / 256, 256, 0, stream>>>(cs, cp, csp, out);
}